// Round 1
// baseline (1318.989 us; speedup 1.0000x reference)
//
#include <hip/hip_runtime.h>
#include <math.h>

#define B_SZ 1024
#define IN_SZ 2048
#define H0_SZ 4096
#define H1_SZ 4096
#define OUT_SZ 1000

// ws layout:
// [0..64)   : double acc[8]: 0=xz 1=sum_ls 2=sum_eps2 3=flowz 4=sum_mu2 5=sum_expls 6=ce_sum
// [256..)   : float msum0[1024]
// [4352..)  : float msum1[1024]
// [16384..) : float h0[1024*4096]
// then      : float h1[1024*4096]
#define WS_MSUM0 256
#define WS_MSUM1 (256 + 4096)
#define WS_H0 16384
#define WS_H1 (16384 + (size_t)B_SZ * H0_SZ * 4)

__device__ __forceinline__ void reduce4_atomic(double v0, double v1, double v2, double v3,
                                               double* d0, double* d1, double* d2, double* d3)
{
    __shared__ double sh[4][4];
    double v[4] = {v0, v1, v2, v3};
    int lane = threadIdx.x & 63, wid = threadIdx.x >> 6;
#pragma unroll
    for (int a = 0; a < 4; ++a) {
        double x = v[a];
#pragma unroll
        for (int o = 32; o > 0; o >>= 1) x += __shfl_down(x, o, 64);
        if (lane == 0) sh[a][wid] = x;
    }
    __syncthreads();
    if (threadIdx.x == 0) {
        double t0 = sh[0][0] + sh[0][1] + sh[0][2] + sh[0][3];
        double t1 = sh[1][0] + sh[1][1] + sh[1][2] + sh[1][3];
        double t2 = sh[2][0] + sh[2][1] + sh[2][2] + sh[2][3];
        double t3 = sh[3][0] + sh[3][1] + sh[3][2] + sh[3][3];
        if (d0) atomicAdd(d0, t0);
        if (d1) atomicAdd(d1, t1);
        if (d2) atomicAdd(d2, t2);
        if (d3) atomicAdd(d3, t3);
    }
}

// ---- weight-array reduction: sum(ls), sum(eps^2), sum(mu^2), sum(exp(ls))
__global__ __launch_bounds__(256) void wred_kernel(const float4* __restrict__ wls,
                                                   const float4* __restrict__ weps,
                                                   const float4* __restrict__ wmu,
                                                   int n4, double* acc)
{
    double s_ls = 0, s_e2 = 0, s_mu2 = 0, s_ex = 0;
    int i = blockIdx.x * blockDim.x + threadIdx.x;
    int stride = gridDim.x * blockDim.x;
    for (; i < n4; i += stride) {
        float4 l = wls[i], e = weps[i], m = wmu[i];
        s_ls += (double)l.x + l.y + l.z + l.w;
        s_e2 += (double)e.x * e.x + (double)e.y * e.y + (double)e.z * e.z + (double)e.w * e.w;
        s_mu2 += (double)m.x * m.x + (double)m.y * m.y + (double)m.z * m.z + (double)m.w * m.w;
        s_ex += (double)__expf(l.x) + __expf(l.y) + __expf(l.z) + __expf(l.w);
    }
    reduce4_atomic(s_ls, s_e2, s_mu2, s_ex, acc + 1, acc + 2, acc + 4, acc + 5);
}

// ---- bias reduction: sum(ls), sum(eps^2)  (no weight-decay terms for biases)
__global__ __launch_bounds__(256) void bred_kernel(const float4* __restrict__ bls,
                                                   const float4* __restrict__ beps,
                                                   int n4, double* acc)
{
    double s_ls = 0, s_e2 = 0;
    int i = blockIdx.x * blockDim.x + threadIdx.x;
    int stride = gridDim.x * blockDim.x;
    for (; i < n4; i += stride) {
        float4 l = bls[i], e = beps[i];
        s_ls += (double)l.x + l.y + l.z + l.w;
        s_e2 += (double)e.x * e.x + (double)e.y * e.y + (double)e.z * e.z + (double)e.w * e.w;
    }
    reduce4_atomic(s_ls, s_e2, 0.0, 0.0, acc + 1, acc + 2, nullptr, nullptr);
}

// ---- GFN z-mask flow: sum(mz*log p + (1-mz)*log(1-p)), p clipped
__global__ __launch_bounds__(256) void flowz_kernel(const int4* __restrict__ mz,
                                                    const float4* __restrict__ p,
                                                    int n4, double* acc)
{
    double s = 0;
    int i = blockIdx.x * blockDim.x + threadIdx.x;
    int stride = gridDim.x * blockDim.x;
    for (; i < n4; i += stride) {
        int4 m = mz[i];
        float4 q = p[i];
        float a0 = fminf(fmaxf(q.x, 1e-6f), 1.0f - 1e-6f);
        float a1 = fminf(fmaxf(q.y, 1e-6f), 1.0f - 1e-6f);
        float a2 = fminf(fmaxf(q.z, 1e-6f), 1.0f - 1e-6f);
        float a3 = fminf(fmaxf(q.w, 1e-6f), 1.0f - 1e-6f);
        s += (double)logf(m.x ? a0 : 1.0f - a0);
        s += (double)logf(m.y ? a1 : 1.0f - a1);
        s += (double)logf(m.z ? a2 : 1.0f - a2);
        s += (double)logf(m.w ? a3 : 1.0f - a3);
    }
    reduce4_atomic(s, 0.0, 0.0, 0.0, acc + 3, nullptr, nullptr, nullptr);
}

// ---- (x @ z_w).sum()
__global__ __launch_bounds__(256) void xz_kernel(const float4* __restrict__ x,
                                                 const float4* __restrict__ zw,
                                                 double* acc)
{
    const int n4 = B_SZ * IN_SZ / 4;
    double s = 0;
    int i = blockIdx.x * blockDim.x + threadIdx.x;
    int stride = gridDim.x * blockDim.x;
    for (; i < n4; i += stride) {
        float4 xv = x[i];
        float4 zv = zw[i & (IN_SZ / 4 - 1)];
        s += (double)xv.x * zv.x + (double)xv.y * zv.y + (double)xv.z * zv.z + (double)xv.w * zv.w;
    }
    reduce4_atomic(s, 0.0, 0.0, 0.0, acc + 0, nullptr, nullptr, nullptr);
}

// ---- per-row mask sums: msum[b] = sum_h mz[b,h]*mask_mu[h]
__global__ __launch_bounds__(256) void msum_kernel(const int* __restrict__ mz,
                                                   const int* __restrict__ mask,
                                                   float* __restrict__ msum, int H)
{
    int b = blockIdx.x;
    const int4* mzr = (const int4*)(mz + (size_t)b * H);
    const int4* mk = (const int4*)mask;
    int s = 0;
    for (int i = threadIdx.x; i < H / 4; i += blockDim.x) {
        int4 m = mzr[i];
        int4 k = mk[i];
        s += m.x * k.x + m.y * k.y + m.z * k.z + m.w * k.w;
    }
#pragma unroll
    for (int o = 32; o > 0; o >>= 1) s += __shfl_down(s, o, 64);
    __shared__ int sh[4];
    if ((threadIdx.x & 63) == 0) sh[threadIdx.x >> 6] = s;
    __syncthreads();
    if (threadIdx.x == 0) msum[b] = (float)(sh[0] + sh[1] + sh[2] + sh[3]);
}

// ---- fused SGEMM: C = epilogue( A @ sample(W)^T + sample(b) )
// EPI 0: leaky + mask*mult, write h (N = 4096).  EPI 1: plain, write pred with N guard.
template <int EPI>
__global__ __launch_bounds__(256) void gemm_kernel(
    const float* __restrict__ A,
    const float* __restrict__ wmu, const float* __restrict__ wls, const float* __restrict__ weps,
    const float* __restrict__ bmu, const float* __restrict__ bls, const float* __restrict__ beps,
    const int* __restrict__ mz, const int* __restrict__ mask_mu, const float* __restrict__ msum,
    float* __restrict__ C, int M, int N, int K)
{
    __shared__ float As[16][132];
    __shared__ float Ws[16][68];
    const int tid = threadIdx.x;
    const int bm = blockIdx.y * 128;
    const int bn = blockIdx.x * 64;
    const int tx = tid & 15;   // n dir
    const int ty = tid >> 4;   // m dir
    const int lr = tid >> 2;       // 0..63
    const int lk = (tid & 3) << 2; // 0,4,8,12

    const int wrow = bn + lr;
    const int wrc = wrow < N ? wrow : N - 1;
    const bool wok = wrow < N;
    const float* pa0 = A + (size_t)(bm + lr) * K + lk;
    const float* pa1 = pa0 + (size_t)64 * K;
    const float* pmu = wmu + (size_t)wrc * K + lk;
    const float* pls = wls + (size_t)wrc * K + lk;
    const float* pep = weps + (size_t)wrc * K + lk;

    float acc[8][4];
#pragma unroll
    for (int i = 0; i < 8; ++i)
#pragma unroll
        for (int j = 0; j < 4; ++j) acc[i][j] = 0.f;

    for (int bk = 0; bk < K; bk += 16) {
        float4 a0 = *(const float4*)(pa0 + bk);
        float4 a1 = *(const float4*)(pa1 + bk);
        float4 mu = *(const float4*)(pmu + bk);
        float4 ls = *(const float4*)(pls + bk);
        float4 ep = *(const float4*)(pep + bk);
        float4 w;
        w.x = mu.x + __expf(ls.x) * ep.x;
        w.y = mu.y + __expf(ls.y) * ep.y;
        w.z = mu.z + __expf(ls.z) * ep.z;
        w.w = mu.w + __expf(ls.w) * ep.w;
        if (!wok) { w.x = w.y = w.z = w.w = 0.f; }
        __syncthreads();
        As[lk + 0][lr] = a0.x; As[lk + 1][lr] = a0.y; As[lk + 2][lr] = a0.z; As[lk + 3][lr] = a0.w;
        As[lk + 0][lr + 64] = a1.x; As[lk + 1][lr + 64] = a1.y; As[lk + 2][lr + 64] = a1.z; As[lk + 3][lr + 64] = a1.w;
        Ws[lk + 0][lr] = w.x; Ws[lk + 1][lr] = w.y; Ws[lk + 2][lr] = w.z; Ws[lk + 3][lr] = w.w;
        __syncthreads();
#pragma unroll
        for (int k = 0; k < 16; ++k) {
            float4 q0 = *(const float4*)&As[k][ty * 4];
            float4 q1 = *(const float4*)&As[k][ty * 4 + 64];
            float4 wv = *(const float4*)&Ws[k][tx * 4];
            float av[8] = {q0.x, q0.y, q0.z, q0.w, q1.x, q1.y, q1.z, q1.w};
            float bv[4] = {wv.x, wv.y, wv.z, wv.w};
#pragma unroll
            for (int i = 0; i < 8; ++i)
#pragma unroll
                for (int j = 0; j < 4; ++j)
                    acc[i][j] = fmaf(av[i], bv[j], acc[i][j]);
        }
    }

    const int col = bn + tx * 4;
    float bias[4];
#pragma unroll
    for (int j = 0; j < 4; ++j) {
        int c = col + j;
        if (c > N - 1) c = N - 1;
        bias[j] = bmu[c] + __expf(bls[c]) * beps[c];
    }
#pragma unroll
    for (int i = 0; i < 8; ++i) {
        int row = bm + ty * 4 + (i & 3) + ((i >> 2) << 6);
        if (EPI == 0) {
            float ms = msum[row];
            float mult = (float)N / (ms + 1e-6f);
            const int4 mzv = *(const int4*)(mz + (size_t)row * N + col);
            const int4 mkv = *(const int4*)(mask_mu + col);
            int mm[4] = {mzv.x * mkv.x, mzv.y * mkv.y, mzv.z * mkv.z, mzv.w * mkv.w};
            float o[4];
#pragma unroll
            for (int j = 0; j < 4; ++j) {
                float v = acc[i][j] + bias[j];
                v = v >= 0.f ? v : 0.01f * v;
                o[j] = v * (float)mm[j] * mult;
            }
            *(float4*)(C + (size_t)row * N + col) = make_float4(o[0], o[1], o[2], o[3]);
        } else {
#pragma unroll
            for (int j = 0; j < 4; ++j) {
                int c = col + j;
                if (c < N) C[(size_t)row * N + c] = acc[i][j] + bias[j];
            }
        }
    }
}

// ---- cross entropy: acc[6] += lse(pred[b]) - pred[b, y[b]]
__global__ __launch_bounds__(256) void ce_kernel(const float* __restrict__ pred,
                                                 const int* __restrict__ y, double* acc)
{
    int b = blockIdx.x;
    const float* pr = pred + (size_t)b * OUT_SZ;
    float mx = -1e30f;
    for (int j = threadIdx.x; j < OUT_SZ; j += 256) mx = fmaxf(mx, pr[j]);
#pragma unroll
    for (int o = 32; o > 0; o >>= 1) mx = fmaxf(mx, __shfl_down(mx, o, 64));
    __shared__ float sm[4];
    if ((threadIdx.x & 63) == 0) sm[threadIdx.x >> 6] = mx;
    __syncthreads();
    mx = fmaxf(fmaxf(sm[0], sm[1]), fmaxf(sm[2], sm[3]));
    double se = 0;
    for (int j = threadIdx.x; j < OUT_SZ; j += 256) se += (double)__expf(pr[j] - mx);
#pragma unroll
    for (int o = 32; o > 0; o >>= 1) se += __shfl_down(se, o, 64);
    __shared__ double sd[4];
    if ((threadIdx.x & 63) == 0) sd[threadIdx.x >> 6] = se;
    __syncthreads();
    if (threadIdx.x == 0) {
        double s = sd[0] + sd[1] + sd[2] + sd[3];
        double lse = (double)mx + log(s);
        atomicAdd(acc + 6, lse - (double)pr[y[b]]);
    }
}

__global__ void finalize_kernel(const double* __restrict__ acc, const int* __restrict__ dss,
                                float* __restrict__ out)
{
    // N_total log-density constant: (8388608+4096+16777216+4096) elements
    const double NTOT = 25174016.0;
    double cst = NTOT * (log(2.0e-5) - 0.91893853320467274178);  // log(2*EPS) - 0.5*log(2*pi)
    double loss = acc[0]                      // (x @ z_w).sum()
                + cst - acc[1] - 0.5 * acc[2] // sum log pw + log pb (analytic)
                + acc[3]                      // z-mask flow
                + (double)(*dss) * (acc[6] / (double)B_SZ)  // NLL
                + 0.01 * (acc[4] + acc[5]);   // weight decay
    out[(size_t)B_SZ * OUT_SZ] = (float)(loss * loss);
}

extern "C" void kernel_launch(void* const* d_in, const int* in_sizes, int n_in,
                              void* d_out, int out_size, void* d_ws, size_t ws_size,
                              hipStream_t stream)
{
    const float* x = (const float*)d_in[0];
    const float* zw = (const float*)d_in[1];
    const float* wmu0 = (const float*)d_in[2];
    const float* wls0 = (const float*)d_in[3];
    const float* bmu0 = (const float*)d_in[4];
    const float* bls0 = (const float*)d_in[5];
    const float* weps0 = (const float*)d_in[6];
    const float* beps0 = (const float*)d_in[7];
    const float* wmu1 = (const float*)d_in[8];
    const float* wls1 = (const float*)d_in[9];
    const float* bmu1 = (const float*)d_in[10];
    const float* bls1 = (const float*)d_in[11];
    const float* weps1 = (const float*)d_in[12];
    const float* beps1 = (const float*)d_in[13];
    const float* wmuo = (const float*)d_in[14];
    const float* wlso = (const float*)d_in[15];
    const float* bmuo = (const float*)d_in[16];
    const float* blso = (const float*)d_in[17];
    const float* wepso = (const float*)d_in[18];
    const float* bepso = (const float*)d_in[19];
    const float* pfz0 = (const float*)d_in[20];
    const float* pfz1 = (const float*)d_in[21];
    const int* y = (const int*)d_in[22];
    const int* mz0 = (const int*)d_in[23];
    const int* mz1 = (const int*)d_in[24];
    const int* mmu0 = (const int*)d_in[25];
    const int* mmu1 = (const int*)d_in[26];
    const int* dss = (const int*)d_in[27];

    double* acc = (double*)d_ws;
    float* msum0 = (float*)((char*)d_ws + WS_MSUM0);
    float* msum1 = (float*)((char*)d_ws + WS_MSUM1);
    float* h0 = (float*)((char*)d_ws + WS_H0);
    float* h1 = (float*)((char*)d_ws + WS_H1);
    float* out = (float*)d_out;

    hipMemsetAsync(d_ws, 0, 64, stream);

    xz_kernel<<<512, 256, 0, stream>>>((const float4*)x, (const float4*)zw, acc);
    wred_kernel<<<1024, 256, 0, stream>>>((const float4*)wls0, (const float4*)weps0,
                                          (const float4*)wmu0, H0_SZ * IN_SZ / 4, acc);
    wred_kernel<<<1024, 256, 0, stream>>>((const float4*)wls1, (const float4*)weps1,
                                          (const float4*)wmu1, H1_SZ * H0_SZ / 4, acc);
    bred_kernel<<<8, 256, 0, stream>>>((const float4*)bls0, (const float4*)beps0, H0_SZ / 4, acc);
    bred_kernel<<<8, 256, 0, stream>>>((const float4*)bls1, (const float4*)beps1, H1_SZ / 4, acc);
    flowz_kernel<<<1024, 256, 0, stream>>>((const int4*)mz0, (const float4*)pfz0, B_SZ * H0_SZ / 4, acc);
    flowz_kernel<<<1024, 256, 0, stream>>>((const int4*)mz1, (const float4*)pfz1, B_SZ * H1_SZ / 4, acc);
    msum_kernel<<<B_SZ, 256, 0, stream>>>(mz0, mmu0, msum0, H0_SZ);
    msum_kernel<<<B_SZ, 256, 0, stream>>>(mz1, mmu1, msum1, H1_SZ);

    gemm_kernel<0><<<dim3(H0_SZ / 64, B_SZ / 128), 256, 0, stream>>>(
        x, wmu0, wls0, weps0, bmu0, bls0, beps0, mz0, mmu0, msum0, h0, B_SZ, H0_SZ, IN_SZ);
    gemm_kernel<0><<<dim3(H1_SZ / 64, B_SZ / 128), 256, 0, stream>>>(
        h0, wmu1, wls1, weps1, bmu1, bls1, beps1, mz1, mmu1, msum1, h1, B_SZ, H1_SZ, H0_SZ);
    gemm_kernel<1><<<dim3((OUT_SZ + 63) / 64, B_SZ / 128), 256, 0, stream>>>(
        h1, wmuo, wlso, wepso, bmuo, blso, bepso, nullptr, nullptr, nullptr, out, B_SZ, OUT_SZ, H1_SZ);

    ce_kernel<<<B_SZ, 256, 0, stream>>>(out, y, acc);
    finalize_kernel<<<1, 1, 0, stream>>>(acc, dss, out);
}

// Round 2
// 746.577 us; speedup vs baseline: 1.7667x; 1.7667x over previous
//
#include <hip/hip_runtime.h>
#include <math.h>

#define B_SZ 1024
#define IN_SZ 2048
#define H0_SZ 4096
#define H1_SZ 4096
#define OUT_SZ 1000

typedef _Float16 f16;
typedef __attribute__((ext_vector_type(4))) _Float16 f16x4;
typedef __attribute__((ext_vector_type(8))) _Float16 f16x8;
typedef __attribute__((ext_vector_type(4))) float f32x4;

// ---------------- ws layout (bytes) ----------------
// acc doubles: 0=xz 1=sum_ls 2=sum_eps2 3=flowz 4=sum_mu2 5=sum_expls 6=ce_sum
#define OFF_MSUM0 256
#define OFF_MSUM1 4352
#define OFF_XH   16384ULL
#define OFF_XL   4210688ULL
#define OFF_H0H  8404992ULL
#define OFF_H0L  16793600ULL
#define OFF_H1H  25182208ULL
#define OFF_H1L  33570816ULL
#define FB_END   41959424ULL
#define OFF_W0H  41959424ULL
#define OFF_W0L  58736640ULL
#define OFF_W1H  75513856ULL
#define OFF_W1L  109068288ULL
#define OFF_WOH  142622720ULL
#define OFF_WOL  151011328ULL
#define OFF_PART 159399936ULL
#define PRE_END  175783936ULL

__device__ __forceinline__ void gload_lds16(const void* g, void* l)
{
    __builtin_amdgcn_global_load_lds((const __attribute__((address_space(1))) void*)g,
                                     (__attribute__((address_space(3))) void*)l, 16, 0, 0);
}

__device__ __forceinline__ void reduce4_atomic(double v0, double v1, double v2, double v3,
                                               double* d0, double* d1, double* d2, double* d3)
{
    __shared__ double sh[4][4];
    double v[4] = {v0, v1, v2, v3};
    int lane = threadIdx.x & 63, wid = threadIdx.x >> 6;
#pragma unroll
    for (int a = 0; a < 4; ++a) {
        double x = v[a];
#pragma unroll
        for (int o = 32; o > 0; o >>= 1) x += __shfl_down(x, o, 64);
        if (lane == 0) sh[a][wid] = x;
    }
    __syncthreads();
    if (threadIdx.x == 0) {
        double t0 = sh[0][0] + sh[0][1] + sh[0][2] + sh[0][3];
        double t1 = sh[1][0] + sh[1][1] + sh[1][2] + sh[1][3];
        double t2 = sh[2][0] + sh[2][1] + sh[2][2] + sh[2][3];
        double t3 = sh[3][0] + sh[3][1] + sh[3][2] + sh[3][3];
        if (d0) atomicAdd(d0, t0);
        if (d1) atomicAdd(d1, t1);
        if (d2) atomicAdd(d2, t2);
        if (d3) atomicAdd(d3, t3);
    }
}

// ---- sample W = mu + exp(ls)*eps into split f16 planes; RED also accumulates
// sum(ls), sum(eps^2), sum(mu^2), sum(exp(ls)) for the flow/decay terms.
template <int RED>
__global__ __launch_bounds__(256) void wsample_kernel(const float4* __restrict__ mu,
                                                      const float4* __restrict__ ls,
                                                      const float4* __restrict__ eps,
                                                      f16x4* __restrict__ hi, f16x4* __restrict__ lo,
                                                      int n4, double* acc)
{
    double s_ls = 0, s_e2 = 0, s_mu2 = 0, s_ex = 0;
    int i = blockIdx.x * blockDim.x + threadIdx.x;
    int stride = gridDim.x * blockDim.x;
    for (; i < n4; i += stride) {
        float4 m = mu[i], l = ls[i], e = eps[i];
        float s0 = __expf(l.x), s1 = __expf(l.y), s2 = __expf(l.z), s3 = __expf(l.w);
        float w0 = fmaf(s0, e.x, m.x), w1 = fmaf(s1, e.y, m.y);
        float w2 = fmaf(s2, e.z, m.z), w3 = fmaf(s3, e.w, m.w);
        f16 h0 = (f16)w0, h1 = (f16)w1, h2 = (f16)w2, h3 = (f16)w3;
        f16x4 hv = {h0, h1, h2, h3};
        f16x4 lv = {(f16)(w0 - (float)h0), (f16)(w1 - (float)h1),
                    (f16)(w2 - (float)h2), (f16)(w3 - (float)h3)};
        hi[i] = hv; lo[i] = lv;
        if (RED) {
            s_ls += (double)l.x + l.y + l.z + l.w;
            s_e2 += (double)e.x * e.x + (double)e.y * e.y + (double)e.z * e.z + (double)e.w * e.w;
            s_mu2 += (double)m.x * m.x + (double)m.y * m.y + (double)m.z * m.z + (double)m.w * m.w;
            s_ex += (double)s0 + s1 + s2 + s3;
        }
    }
    if (RED) reduce4_atomic(s_ls, s_e2, s_mu2, s_ex, acc + 1, acc + 2, acc + 4, acc + 5);
}

// ---- fallback weight reduction (no presample)
__global__ __launch_bounds__(256) void wred_kernel(const float4* __restrict__ wls,
                                                   const float4* __restrict__ weps,
                                                   const float4* __restrict__ wmu,
                                                   int n4, double* acc)
{
    double s_ls = 0, s_e2 = 0, s_mu2 = 0, s_ex = 0;
    int i = blockIdx.x * blockDim.x + threadIdx.x;
    int stride = gridDim.x * blockDim.x;
    for (; i < n4; i += stride) {
        float4 l = wls[i], e = weps[i], m = wmu[i];
        s_ls += (double)l.x + l.y + l.z + l.w;
        s_e2 += (double)e.x * e.x + (double)e.y * e.y + (double)e.z * e.z + (double)e.w * e.w;
        s_mu2 += (double)m.x * m.x + (double)m.y * m.y + (double)m.z * m.z + (double)m.w * m.w;
        s_ex += (double)__expf(l.x) + __expf(l.y) + __expf(l.z) + __expf(l.w);
    }
    reduce4_atomic(s_ls, s_e2, s_mu2, s_ex, acc + 1, acc + 2, acc + 4, acc + 5);
}

__global__ __launch_bounds__(256) void bred_kernel(const float4* __restrict__ bls,
                                                   const float4* __restrict__ beps,
                                                   int n4, double* acc)
{
    double s_ls = 0, s_e2 = 0;
    int i = blockIdx.x * blockDim.x + threadIdx.x;
    int stride = gridDim.x * blockDim.x;
    for (; i < n4; i += stride) {
        float4 l = bls[i], e = beps[i];
        s_ls += (double)l.x + l.y + l.z + l.w;
        s_e2 += (double)e.x * e.x + (double)e.y * e.y + (double)e.z * e.z + (double)e.w * e.w;
    }
    reduce4_atomic(s_ls, s_e2, 0.0, 0.0, acc + 1, acc + 2, nullptr, nullptr);
}

__global__ __launch_bounds__(256) void flowz_kernel(const int4* __restrict__ mz,
                                                    const float4* __restrict__ p,
                                                    int n4, double* acc)
{
    double s = 0;
    int i = blockIdx.x * blockDim.x + threadIdx.x;
    int stride = gridDim.x * blockDim.x;
    for (; i < n4; i += stride) {
        int4 m = mz[i];
        float4 q = p[i];
        float a0 = fminf(fmaxf(q.x, 1e-6f), 1.0f - 1e-6f);
        float a1 = fminf(fmaxf(q.y, 1e-6f), 1.0f - 1e-6f);
        float a2 = fminf(fmaxf(q.z, 1e-6f), 1.0f - 1e-6f);
        float a3 = fminf(fmaxf(q.w, 1e-6f), 1.0f - 1e-6f);
        s += (double)logf(m.x ? a0 : 1.0f - a0);
        s += (double)logf(m.y ? a1 : 1.0f - a1);
        s += (double)logf(m.z ? a2 : 1.0f - a2);
        s += (double)logf(m.w ? a3 : 1.0f - a3);
    }
    reduce4_atomic(s, 0.0, 0.0, 0.0, acc + 3, nullptr, nullptr, nullptr);
}

// ---- split x into f16 hi/lo planes, fused with (x @ z_w).sum()
__global__ __launch_bounds__(256) void splitx_kernel(const float4* __restrict__ x,
                                                     const float4* __restrict__ zw,
                                                     f16x4* __restrict__ xh, f16x4* __restrict__ xl,
                                                     double* acc)
{
    const int n4 = B_SZ * IN_SZ / 4;
    double s = 0;
    int i = blockIdx.x * blockDim.x + threadIdx.x;
    int stride = gridDim.x * blockDim.x;
    for (; i < n4; i += stride) {
        float4 v = x[i];
        float4 z = zw[i & (IN_SZ / 4 - 1)];
        s += (double)v.x * z.x + (double)v.y * z.y + (double)v.z * z.z + (double)v.w * z.w;
        f16 h0 = (f16)v.x, h1 = (f16)v.y, h2 = (f16)v.z, h3 = (f16)v.w;
        f16x4 hv = {h0, h1, h2, h3};
        f16x4 lv = {(f16)(v.x - (float)h0), (f16)(v.y - (float)h1),
                    (f16)(v.z - (float)h2), (f16)(v.w - (float)h3)};
        xh[i] = hv; xl[i] = lv;
    }
    reduce4_atomic(s, 0.0, 0.0, 0.0, acc + 0, nullptr, nullptr, nullptr);
}

__global__ __launch_bounds__(256) void msum_kernel(const int* __restrict__ mz,
                                                   const int* __restrict__ mask,
                                                   float* __restrict__ msum, int H)
{
    int b = blockIdx.x;
    const int4* mzr = (const int4*)(mz + (size_t)b * H);
    const int4* mk = (const int4*)mask;
    int s = 0;
    for (int i = threadIdx.x; i < H / 4; i += blockDim.x) {
        int4 m = mzr[i];
        int4 k = mk[i];
        s += m.x * k.x + m.y * k.y + m.z * k.z + m.w * k.w;
    }
#pragma unroll
    for (int o = 32; o > 0; o >>= 1) s += __shfl_down(s, o, 64);
    __shared__ int sh[4];
    if ((threadIdx.x & 63) == 0) sh[threadIdx.x >> 6] = s;
    __syncthreads();
    if (threadIdx.x == 0) msum[b] = (float)(sh[0] + sh[1] + sh[2] + sh[3]);
}

// ---- split-f16 MFMA GEMM: C = A @ sample(W)^T (+ bias, + epilogue)
// A given as hi/lo f16 planes [M][K]; W either presampled hi/lo planes (WPRE=1)
// or sampled on the fly from mu/ls/eps (WPRE=0).
// EPI 0: bias+leaky+mask, write h hi/lo planes (N=4096).
// EPI 1: bias, write pred f32 with col<N guard.
// EPI 2: no bias, write f32 partial at Cf[z*B*OUT + row*N + col] (split-K, WPRE=1 only).
// Geometry: 128x128 tile, BK=32, 512 threads = 8 waves (2 row x 4 col), wave tile 64x32.
// LDS per plane: [rb 0..7][kc 0..3][r 0..15][e 0..7] halves -> frag read = lane*16B linear.
template <int EPI, int WPRE>
__global__ __launch_bounds__(512) void mgemm(
    const f16* __restrict__ Ah, const f16* __restrict__ Al,
    const f16* __restrict__ Wh, const f16* __restrict__ Wl,
    const float* __restrict__ wmu, const float* __restrict__ wls, const float* __restrict__ weps,
    const float* __restrict__ bmu, const float* __restrict__ bls, const float* __restrict__ beps,
    const int* __restrict__ mz, const int* __restrict__ mask_mu, const float* __restrict__ msum,
    float* __restrict__ Cf, f16* __restrict__ Chh, f16* __restrict__ Chl,
    int K, int N)
{
    __shared__ __align__(16) f16 lds[16384];  // 4 planes x 8KB
    const int tid = threadIdx.x;
    const int wv = tid >> 6, lane = tid & 63;
    const int wr = wv >> 2, wc = wv & 3;
    const int bm = blockIdx.y * 128, bn = blockIdx.x * 128;

    // staging setup (global_load_lds planes)
    const int nplanes = WPRE ? 4 : 2;
    const f16* ssrc = nullptr;
    size_t goffs[4];
    f16* lptr[4];
    if (wv < nplanes * 2) {
        const int p = wv >> 1, half = wv & 1;
        ssrc = (p == 0) ? Ah : (p == 1) ? Al : (p == 2) ? Wh : Wl;
        const int rowbase = (p < 2) ? bm : bn;
#pragma unroll
        for (int i = 0; i < 4; ++i) {
            const int rb = half * 4 + i;
            goffs[i] = (size_t)(rowbase + rb * 16 + (lane & 15)) * K + (lane >> 4) * 8;
            lptr[i] = lds + p * 4096 + rb * 512;
        }
    }

    // on-the-fly W sampling setup (WPRE=0)
    int wrow = 0, wok = 1;
    size_t wgbase = 0;
    f16* wdst = nullptr;
    if (!WPRE) {
        const int row = tid >> 2, kc = tid & 3;
        wrow = bn + row;
        wok = (EPI == 0) ? 1 : (wrow < N);
        const int wrc = wok ? wrow : N - 1;
        wgbase = (size_t)wrc * K + kc * 8;
        wdst = lds + 2 * 4096 + (row >> 4) * 512 + kc * 128 + (row & 15) * 8;
    }

    f32x4 acc[4][2];
#pragma unroll
    for (int m = 0; m < 4; ++m)
#pragma unroll
        for (int n = 0; n < 2; ++n) acc[m][n] = (f32x4){0.f, 0.f, 0.f, 0.f};

    const int kz = (EPI == 2) ? blockIdx.z : 0;
    const int kbeg = (EPI == 2) ? kz * (K >> 2) : 0;
    const int kend = (EPI == 2) ? kbeg + (K >> 2) : K;

    for (int bk = kbeg; bk < kend; bk += 32) {
        __syncthreads();
        if (wv < nplanes * 2) {
#pragma unroll
            for (int i = 0; i < 4; ++i)
                gload_lds16(ssrc + goffs[i] + bk, lptr[i]);
        }
        if (!WPRE) {
            const size_t g = wgbase + bk;
            float4 m0 = *(const float4*)(wmu + g), m1 = *(const float4*)(wmu + g + 4);
            float4 l0 = *(const float4*)(wls + g), l1 = *(const float4*)(wls + g + 4);
            float4 e0 = *(const float4*)(weps + g), e1 = *(const float4*)(weps + g + 4);
            float w[8];
            w[0] = fmaf(__expf(l0.x), e0.x, m0.x); w[1] = fmaf(__expf(l0.y), e0.y, m0.y);
            w[2] = fmaf(__expf(l0.z), e0.z, m0.z); w[3] = fmaf(__expf(l0.w), e0.w, m0.w);
            w[4] = fmaf(__expf(l1.x), e1.x, m1.x); w[5] = fmaf(__expf(l1.y), e1.y, m1.y);
            w[6] = fmaf(__expf(l1.z), e1.z, m1.z); w[7] = fmaf(__expf(l1.w), e1.w, m1.w);
            f16x8 whi, wlo;
#pragma unroll
            for (int t = 0; t < 8; ++t) {
                float v = (EPI != 0 && !wok) ? 0.f : w[t];
                f16 h = (f16)v;
                whi[t] = h;
                wlo[t] = (f16)(v - (float)h);
            }
            *(f16x8*)wdst = whi;
            *(f16x8*)(wdst + 4096) = wlo;
        }
        __syncthreads();

        f16x8 ah[4], al[4], bh[2], bl[2];
#pragma unroll
        for (int m = 0; m < 4; ++m) {
            ah[m] = *(const f16x8*)(lds + (wr * 4 + m) * 512 + lane * 8);
            al[m] = *(const f16x8*)(lds + 4096 + (wr * 4 + m) * 512 + lane * 8);
        }
#pragma unroll
        for (int n = 0; n < 2; ++n) {
            bh[n] = *(const f16x8*)(lds + 8192 + (wc * 2 + n) * 512 + lane * 8);
            bl[n] = *(const f16x8*)(lds + 12288 + (wc * 2 + n) * 512 + lane * 8);
        }
#pragma unroll
        for (int m = 0; m < 4; ++m)
#pragma unroll
            for (int n = 0; n < 2; ++n) {
                acc[m][n] = __builtin_amdgcn_mfma_f32_16x16x32_f16(ah[m], bh[n], acc[m][n], 0, 0, 0);
                acc[m][n] = __builtin_amdgcn_mfma_f32_16x16x32_f16(ah[m], bl[n], acc[m][n], 0, 0, 0);
                acc[m][n] = __builtin_amdgcn_mfma_f32_16x16x32_f16(al[m], bh[n], acc[m][n], 0, 0, 0);
            }
    }

    // epilogue: C[row][col], col = bn + wc*32 + n*16 + (lane&15),
    // row = bm + wr*64 + m*16 + (lane>>4)*4 + j
    const int c0 = bn + wc * 32;
#pragma unroll
    for (int n = 0; n < 2; ++n) {
        const int col = c0 + n * 16 + (lane & 15);
        if (EPI == 1 && col >= N) continue;
        float bias = 0.f;
        int mk = 0;
        if (EPI != 2) bias = bmu[col] + __expf(bls[col]) * beps[col];
        if (EPI == 0) mk = mask_mu[col];
#pragma unroll
        for (int m = 0; m < 4; ++m) {
            const int rowb = bm + wr * 64 + m * 16 + (lane >> 4) * 4;
#pragma unroll
            for (int j = 0; j < 4; ++j) {
                const int row = rowb + j;
                float v = acc[m][n][j] + bias;
                if (EPI == 0) {
                    v = v >= 0.f ? v : 0.01f * v;
                    const float mult = (float)H0_SZ / (msum[row] + 1e-6f);
                    const int mm = mz[(size_t)row * N + col] * mk;
                    v = v * (float)mm * mult;
                    const f16 hh = (f16)v;
                    Chh[(size_t)row * N + col] = hh;
                    Chl[(size_t)row * N + col] = (f16)(v - (float)hh);
                } else if (EPI == 1) {
                    Cf[(size_t)row * N + col] = v;
                } else {
                    Cf[(size_t)kz * (B_SZ * OUT_SZ) + (size_t)row * N + col] = v;
                }
            }
        }
    }
}

// ---- CE over split-K partials: pred = sum_s part[s] + bias; acc[6] += lse - pred[y]
__global__ __launch_bounds__(256) void ce_fused_kernel(const float* __restrict__ part,
                                                       const float* __restrict__ bmu,
                                                       const float* __restrict__ bls,
                                                       const float* __restrict__ beps,
                                                       const int* __restrict__ y,
                                                       float* __restrict__ pred, double* acc)
{
    const int b = blockIdx.x;
    const size_t PS = (size_t)B_SZ * OUT_SZ;
    float mx = -1e30f;
    for (int j = threadIdx.x; j < OUT_SZ; j += 256) {
        const size_t o = (size_t)b * OUT_SZ + j;
        float v = part[o] + part[o + PS] + part[o + 2 * PS] + part[o + 3 * PS];
        v += bmu[j] + __expf(bls[j]) * beps[j];
        pred[o] = v;
        mx = fmaxf(mx, v);
    }
#pragma unroll
    for (int o = 32; o > 0; o >>= 1) mx = fmaxf(mx, __shfl_down(mx, o, 64));
    __shared__ float sm[4];
    if ((threadIdx.x & 63) == 0) sm[threadIdx.x >> 6] = mx;
    __syncthreads();
    mx = fmaxf(fmaxf(sm[0], sm[1]), fmaxf(sm[2], sm[3]));
    double se = 0;
    for (int j = threadIdx.x; j < OUT_SZ; j += 256)
        se += (double)__expf(pred[(size_t)b * OUT_SZ + j] - mx);
#pragma unroll
    for (int o = 32; o > 0; o >>= 1) se += __shfl_down(se, o, 64);
    __shared__ double sd[4];
    if ((threadIdx.x & 63) == 0) sd[threadIdx.x >> 6] = se;
    __syncthreads();
    if (threadIdx.x == 0) {
        double lse = (double)mx + log(sd[0] + sd[1] + sd[2] + sd[3]);
        atomicAdd(acc + 6, lse - (double)pred[(size_t)b * OUT_SZ + y[b]]);
    }
}

__global__ __launch_bounds__(256) void ce_kernel(const float* __restrict__ pred,
                                                 const int* __restrict__ y, double* acc)
{
    int b = blockIdx.x;
    const float* pr = pred + (size_t)b * OUT_SZ;
    float mx = -1e30f;
    for (int j = threadIdx.x; j < OUT_SZ; j += 256) mx = fmaxf(mx, pr[j]);
#pragma unroll
    for (int o = 32; o > 0; o >>= 1) mx = fmaxf(mx, __shfl_down(mx, o, 64));
    __shared__ float sm[4];
    if ((threadIdx.x & 63) == 0) sm[threadIdx.x >> 6] = mx;
    __syncthreads();
    mx = fmaxf(fmaxf(sm[0], sm[1]), fmaxf(sm[2], sm[3]));
    double se = 0;
    for (int j = threadIdx.x; j < OUT_SZ; j += 256) se += (double)__expf(pr[j] - mx);
#pragma unroll
    for (int o = 32; o > 0; o >>= 1) se += __shfl_down(se, o, 64);
    __shared__ double sd[4];
    if ((threadIdx.x & 63) == 0) sd[threadIdx.x >> 6] = se;
    __syncthreads();
    if (threadIdx.x == 0) {
        double lse = (double)mx + log(sd[0] + sd[1] + sd[2] + sd[3]);
        atomicAdd(acc + 6, lse - (double)pr[y[b]]);
    }
}

__global__ void finalize_kernel(const double* __restrict__ acc, const int* __restrict__ dss,
                                float* __restrict__ out)
{
    const double NTOT = 25174016.0;  // elements in pw0+pb0+pw1+pb1
    double cst = NTOT * (log(2.0e-5) - 0.91893853320467274178);
    double loss = acc[0]
                + cst - acc[1] - 0.5 * acc[2]
                + acc[3]
                + (double)(*dss) * (acc[6] / (double)B_SZ)
                + 0.01 * (acc[4] + acc[5]);
    out[(size_t)B_SZ * OUT_SZ] = (float)(loss * loss);
}

extern "C" void kernel_launch(void* const* d_in, const int* in_sizes, int n_in,
                              void* d_out, int out_size, void* d_ws, size_t ws_size,
                              hipStream_t stream)
{
    const float* x = (const float*)d_in[0];
    const float* zw = (const float*)d_in[1];
    const float* wmu0 = (const float*)d_in[2];
    const float* wls0 = (const float*)d_in[3];
    const float* bmu0 = (const float*)d_in[4];
    const float* bls0 = (const float*)d_in[5];
    const float* weps0 = (const float*)d_in[6];
    const float* beps0 = (const float*)d_in[7];
    const float* wmu1 = (const float*)d_in[8];
    const float* wls1 = (const float*)d_in[9];
    const float* bmu1 = (const float*)d_in[10];
    const float* bls1 = (const float*)d_in[11];
    const float* weps1 = (const float*)d_in[12];
    const float* beps1 = (const float*)d_in[13];
    const float* wmuo = (const float*)d_in[14];
    const float* wlso = (const float*)d_in[15];
    const float* bmuo = (const float*)d_in[16];
    const float* blso = (const float*)d_in[17];
    const float* wepso = (const float*)d_in[18];
    const float* bepso = (const float*)d_in[19];
    const float* pfz0 = (const float*)d_in[20];
    const float* pfz1 = (const float*)d_in[21];
    const int* y = (const int*)d_in[22];
    const int* mz0 = (const int*)d_in[23];
    const int* mz1 = (const int*)d_in[24];
    const int* mmu0 = (const int*)d_in[25];
    const int* mmu1 = (const int*)d_in[26];
    const int* dss = (const int*)d_in[27];

    char* ws = (char*)d_ws;
    double* acc = (double*)ws;
    float* msum0 = (float*)(ws + OFF_MSUM0);
    float* msum1 = (float*)(ws + OFF_MSUM1);
    f16* xh = (f16*)(ws + OFF_XH);
    f16* xl = (f16*)(ws + OFF_XL);
    f16* h0h = (f16*)(ws + OFF_H0H);
    f16* h0l = (f16*)(ws + OFF_H0L);
    f16* h1h = (f16*)(ws + OFF_H1H);
    f16* h1l = (f16*)(ws + OFF_H1L);
    f16* w0h = (f16*)(ws + OFF_W0H);
    f16* w0l = (f16*)(ws + OFF_W0L);
    f16* w1h = (f16*)(ws + OFF_W1H);
    f16* w1l = (f16*)(ws + OFF_W1L);
    f16* woh = (f16*)(ws + OFF_WOH);
    f16* wol = (f16*)(ws + OFF_WOL);
    float* part = (float*)(ws + OFF_PART);
    float* out = (float*)d_out;

    const bool pre = ws_size >= (size_t)PRE_END;

    hipMemsetAsync(acc, 0, 64, stream);
    splitx_kernel<<<1024, 256, 0, stream>>>((const float4*)x, (const float4*)zw,
                                            (f16x4*)xh, (f16x4*)xl, acc);
    if (pre) {
        hipMemsetAsync(woh, 0, 2 * 8388608ULL, stream);  // zero-pad Wo planes (rows 1000..1023)
        wsample_kernel<1><<<2048, 256, 0, stream>>>((const float4*)wmu0, (const float4*)wls0,
                                                    (const float4*)weps0, (f16x4*)w0h, (f16x4*)w0l,
                                                    H0_SZ * IN_SZ / 4, acc);
        wsample_kernel<1><<<2048, 256, 0, stream>>>((const float4*)wmu1, (const float4*)wls1,
                                                    (const float4*)weps1, (f16x4*)w1h, (f16x4*)w1l,
                                                    H1_SZ * H0_SZ / 4, acc);
        wsample_kernel<0><<<1024, 256, 0, stream>>>((const float4*)wmuo, (const float4*)wlso,
                                                    (const float4*)wepso, (f16x4*)woh, (f16x4*)wol,
                                                    OUT_SZ * H1_SZ / 4, acc);
    } else {
        wred_kernel<<<1024, 256, 0, stream>>>((const float4*)wls0, (const float4*)weps0,
                                              (const float4*)wmu0, H0_SZ * IN_SZ / 4, acc);
        wred_kernel<<<1024, 256, 0, stream>>>((const float4*)wls1, (const float4*)weps1,
                                              (const float4*)wmu1, H1_SZ * H0_SZ / 4, acc);
    }
    bred_kernel<<<8, 256, 0, stream>>>((const float4*)bls0, (const float4*)beps0, H0_SZ / 4, acc);
    bred_kernel<<<8, 256, 0, stream>>>((const float4*)bls1, (const float4*)beps1, H1_SZ / 4, acc);
    flowz_kernel<<<1024, 256, 0, stream>>>((const int4*)mz0, (const float4*)pfz0, B_SZ * H0_SZ / 4, acc);
    flowz_kernel<<<1024, 256, 0, stream>>>((const int4*)mz1, (const float4*)pfz1, B_SZ * H1_SZ / 4, acc);
    msum_kernel<<<B_SZ, 256, 0, stream>>>(mz0, mmu0, msum0, H0_SZ);
    msum_kernel<<<B_SZ, 256, 0, stream>>>(mz1, mmu1, msum1, H1_SZ);

    if (pre) {
        mgemm<0, 1><<<dim3(32, 8), 512, 0, stream>>>(
            xh, xl, w0h, w0l, nullptr, nullptr, nullptr,
            bmu0, bls0, beps0, mz0, mmu0, msum0, nullptr, h0h, h0l, IN_SZ, H0_SZ);
        mgemm<0, 1><<<dim3(32, 8), 512, 0, stream>>>(
            h0h, h0l, w1h, w1l, nullptr, nullptr, nullptr,
            bmu1, bls1, beps1, mz1, mmu1, msum1, nullptr, h1h, h1l, H0_SZ, H1_SZ);
        mgemm<2, 1><<<dim3(8, 8, 4), 512, 0, stream>>>(
            h1h, h1l, woh, wol, nullptr, nullptr, nullptr,
            nullptr, nullptr, nullptr, nullptr, nullptr, nullptr, part, nullptr, nullptr,
            H1_SZ, OUT_SZ);
        ce_fused_kernel<<<B_SZ, 256, 0, stream>>>(part, bmuo, blso, bepso, y, out, acc);
    } else {
        mgemm<0, 0><<<dim3(32, 8), 512, 0, stream>>>(
            xh, xl, nullptr, nullptr, wmu0, wls0, weps0,
            bmu0, bls0, beps0, mz0, mmu0, msum0, nullptr, h0h, h0l, IN_SZ, H0_SZ);
        mgemm<0, 0><<<dim3(32, 8), 512, 0, stream>>>(
            h0h, h0l, nullptr, nullptr, wmu1, wls1, weps1,
            bmu1, bls1, beps1, mz1, mmu1, msum1, nullptr, h1h, h1l, H0_SZ, H1_SZ);
        mgemm<1, 0><<<dim3(8, 8), 512, 0, stream>>>(
            h1h, h1l, nullptr, nullptr, wmuo, wlso, wepso,
            bmuo, blso, bepso, nullptr, nullptr, nullptr, out, nullptr, nullptr,
            H1_SZ, OUT_SZ);
        ce_kernel<<<B_SZ, 256, 0, stream>>>(out, y, acc);
    }
    finalize_kernel<<<1, 1, 0, stream>>>(acc, dss, out);
}